// Round 9
// baseline (453.880 us; speedup 1.0000x reference)
//
#include <hip/hip_runtime.h>
#include <hip/hip_bf16.h>

#define NN 50000
#define EE 1000000
static constexpr float EPSV = 1e-3f;

typedef __attribute__((ext_vector_type(8))) short short8;
typedef __attribute__((ext_vector_type(4))) float fx4;

__device__ inline float blo(unsigned u) { return __uint_as_float(u << 16); }
__device__ inline float bhi(unsigned u) { return __uint_as_float(u & 0xffff0000u); }
__device__ inline unsigned short f2b(float f) {
    __hip_bfloat16 h = __float2bfloat16(f);
    return *(unsigned short*)&h;
}
__device__ inline unsigned pack2(float a, float b) {
    return (unsigned)f2b(a) | ((unsigned)f2b(b) << 16);
}

// async global->LDS DMA, 16 B per lane
__device__ inline void gload_lds16(const unsigned short* g, unsigned short* ldsbase) {
    __builtin_amdgcn_global_load_lds(
        (const __attribute__((address_space(1))) unsigned int*)(const void*)g,
        (__attribute__((address_space(3))) unsigned int*)(void*)ldsbase, 16, 0, 0);
}

// ---------------- setup: weight transposes/converts ----------------

#define WB1 256    // 256*256/256
#define WB2 128
#define WB3 64

__global__ void setup_kernel(const float* __restrict__ wg1, const float* __restrict__ ws1,
                             unsigned short* __restrict__ Wt1,
                             const float* __restrict__ wg2, const float* __restrict__ ws2,
                             unsigned short* __restrict__ Wt2,
                             const float* __restrict__ wg3, const float* __restrict__ ws3,
                             unsigned short* __restrict__ Wt3) {
    int b = blockIdx.x;
    int t = threadIdx.x;
    if (b < WB1) {
        int idx = b * 256 + t;              // [0, 65536)
        int n = idx >> 8, k = idx & 255;    // K=256, Fo=128, N2=256
        float v = (n < 128) ? wg1[(size_t)k * 128 + n]
                            : ws1[(size_t)k * 128 + (n - 128)];
        Wt1[idx] = f2b(v);
    } else if (b < WB1 + WB2) {
        int idx = (b - WB1) * 256 + t;      // [0, 32768)
        int n = idx >> 7, k = idx & 127;    // K=128, Fo=128, N2=256
        float v = (n < 128) ? wg2[(size_t)k * 128 + n]
                            : ws2[(size_t)k * 128 + (n - 128)];
        Wt2[idx] = f2b(v);
    } else {
        int idx = (b - WB1 - WB2) * 256 + t; // [0, 16384)
        int n = idx >> 7, k = idx & 127;     // K=128, Fo=40, N2=128
        float v = 0.f;
        if (n < 40) v = wg3[(size_t)k * 40 + n];
        else if (n < 80) v = ws3[(size_t)k * 40 + (n - 40)];
        Wt3[idx] = f2b(v);
    }
}

// ---------------- atomic-free CSR build: LDS histogram chain ----------------
// R2/R7: global atomic RMW costs ~15 cyc/op at TCC regardless of address
// distribution -> eliminate the 1M global atomics entirely via LDS histograms.

#define NB 64        // histogram chunks (64*15625 == EE exactly)
#define CHUNK 15625
#define QN 12500     // bins per quarter pass (50 KB LDS)
#define XB 12500     // x->bf16 conversion blocks co-scheduled into hist launch

// H1: per-chunk LDS histogram -> cnt[64][50000] u16; + x->bf16 conversion
__global__ __launch_bounds__(256) void hist_kernel(const int* __restrict__ ei,
                                                   const float4* __restrict__ x,
                                                   uint2* __restrict__ xb,
                                                   unsigned short* __restrict__ cnt) {
    __shared__ unsigned bins[QN];
    int b = blockIdx.x;
    int t = threadIdx.x;
    if (b >= NB) {
        int i = (b - NB) * 256 + t;  // [0, 3.2M)
        float4 v = x[i];
        xb[i] = make_uint2(pack2(v.x, v.y), pack2(v.z, v.w));
        return;
    }
    int e0 = b * CHUNK;
#pragma unroll 1
    for (int q = 0; q < 4; ++q) {
        int qb = q * QN;
        for (int i = t; i < QN; i += 256) bins[i] = 0;
        __syncthreads();
        for (int e = e0 + t; e < e0 + CHUNK; e += 256) {
            unsigned r = (unsigned)ei[EE + e] - (unsigned)qb;
            if (r < (unsigned)QN) atomicAdd(&bins[r], 1u);
        }
        __syncthreads();
        unsigned* crow = (unsigned*)(cnt + (size_t)b * 50000 + qb);
        for (int i = t; i < QN / 2; i += 256)
            crow[i] = bins[2 * i] | (bins[2 * i + 1] << 16);
        __syncthreads();
    }
}

// column sums: tot[n] = sum_b cnt[b][n]
__global__ __launch_bounds__(256) void colsum_kernel(const unsigned short* __restrict__ cnt,
                                                     unsigned* __restrict__ tot) {
    __shared__ unsigned s[256];
    int t = threadIdx.x;
    int n = blockIdx.x * 128 + (t & 127);
    int p = t >> 7;
    unsigned acc = 0;
    if (n < NN)
        for (int b = p; b < NB; b += 2) acc += cnt[(size_t)b * 50000 + n];
    s[t] = acc;
    __syncthreads();
    if (t < 128 && n < NN) tot[n] = s[t] + s[t + 128];
}

__global__ __launch_bounds__(1024) void totsum_kernel(const unsigned* __restrict__ tot,
                                                      int* __restrict__ bsum) {
    __shared__ int s[1024];
    const int t = threadIdx.x;
    int idx = blockIdx.x * 1024 + t;
    s[t] = (idx < NN) ? (int)tot[idx] : 0;
    __syncthreads();
#pragma unroll
    for (int off = 512; off > 0; off >>= 1) {
        if (t < off) s[t] += s[t + off];
        __syncthreads();
    }
    if (t == 0) bsum[blockIdx.x] = s[0];
}

__global__ __launch_bounds__(64) void scanB_kernel(const int* __restrict__ bsum,
                                                   int* __restrict__ bpre, int nb) {
    int t = threadIdx.x;
    int v = (t < nb) ? bsum[t] : 0;
    int own = v;
#pragma unroll
    for (int off = 1; off < 64; off <<= 1) {
        int u = __shfl_up(v, off);
        if (t >= off) v += u;
    }
    if (t < nb) bpre[t] = v - own;
}

__global__ __launch_bounds__(1024) void scanC_kernel(const unsigned* __restrict__ tot,
                                                     const int* __restrict__ bpre,
                                                     int* __restrict__ rowstart) {
    __shared__ int s[1024];
    const int t = threadIdx.x;
    int idx = blockIdx.x * 1024 + t;
    int v = (idx < NN) ? (int)tot[idx] : 0;
    s[t] = v;
    __syncthreads();
#pragma unroll
    for (int off = 1; off < 1024; off <<= 1) {
        int u = (t >= off) ? s[t - off] : 0;
        __syncthreads();
        s[t] += u;
        __syncthreads();
    }
    if (idx < NN) rowstart[idx] = s[t] - v + bpre[blockIdx.x];
    if (idx == 0) rowstart[NN] = EE;
}

// H2: prefix[b][n] = sum_{b'<b} cnt[b'][n]  (u16 — per-node degree << 65536)
__global__ __launch_bounds__(256) void base_kernel(const unsigned short* __restrict__ cnt,
                                                   unsigned short* __restrict__ prefix) {
    int t = threadIdx.x;
    if (t >= 128) return;
    int n = blockIdx.x * 128 + t;
    if (n >= NN) return;
    unsigned running = 0;
#pragma unroll 8
    for (int b = 0; b < NB; ++b) {
        unsigned c = cnt[(size_t)b * 50000 + n];
        prefix[(size_t)b * 50000 + n] = (unsigned short)running;
        running += c;
    }
}

// H3: scatter fill via LDS position counters (rowstart + prefix). Zero global atomics.
__global__ __launch_bounds__(256) void fill2_kernel(const int* __restrict__ ei,
                                                    const float* __restrict__ ew,
                                                    const int* __restrict__ rowstart,
                                                    const unsigned short* __restrict__ prefix,
                                                    unsigned* __restrict__ eprec4,
                                                    float* __restrict__ wtmp) {
    __shared__ unsigned bins[QN];
    int t = threadIdx.x;
    int b = blockIdx.x >> 2;
    int q = blockIdx.x & 3;
    int qb = q * QN;
    const unsigned short* pf = prefix + (size_t)b * 50000 + qb;
    const int* rs = rowstart + qb;
    for (int i = t; i < QN; i += 256) bins[i] = (unsigned)rs[i] + (unsigned)pf[i];
    __syncthreads();
    int e0 = b * CHUNK;
    for (int e = e0 + t; e < e0 + CHUNK; e += 256) {
        unsigned r = (unsigned)ei[EE + e] - (unsigned)qb;
        if (r < (unsigned)QN) {
            unsigned pos = atomicAdd(&bins[r], 1u);
            eprec4[pos] = (unsigned)ei[e] << 16;
            wtmp[pos] = ew[e];
        }
    }
}

// H4: per-row fp32 weight sum -> dinv
__global__ __launch_bounds__(256) void dinv_kernel(const int* __restrict__ rowstart,
                                                   const float* __restrict__ wtmp,
                                                   float* __restrict__ dinv) {
    int wave = threadIdx.x >> 6, lane = threadIdx.x & 63;
    int n = blockIdx.x * 4 + wave;
    if (n >= NN) return;
    int beg = rowstart[n], end = rowstart[n + 1];
    float a = 0.f;
    for (int i = beg + lane; i < end; i += 64) a += wtmp[i];
#pragma unroll
    for (int off = 32; off > 0; off >>= 1) a += __shfl_xor(a, off);
    if (lane == 0) dinv[n] = (a > 0.f) ? rsqrtf(a) : 0.f;
}

// H5: w = dinv[src] * ew * dinv[dst], single bf16 rounding into eprec4 low16
__global__ __launch_bounds__(256) void rescale_kernel(const int* __restrict__ rowstart,
                                                      const float* __restrict__ wtmp,
                                                      const float* __restrict__ dinv,
                                                      unsigned* __restrict__ eprec4) {
    int wave = threadIdx.x >> 6, lane = threadIdx.x & 63;
    int n = blockIdx.x * 4 + wave;
    if (n >= NN) return;
    float dn = dinv[n];
    int beg = rowstart[n], end = rowstart[n + 1];
    for (int i = beg + lane; i < end; i += 64) {
        unsigned rec = eprec4[i];
        float w = wtmp[i] * dinv[rec >> 16] * dn;
        eprec4[i] = (rec & 0xffff0000u) | (unsigned)f2b(w);
    }
}

// ---------------- MFMA dual GEMM: 64x128 tile, BK=32, 2-phase dbuf ----------------

__device__ __forceinline__ void gemm2ph_body(int bx, int by,
                                             const unsigned short* __restrict__ Ab,
                                             const unsigned short* __restrict__ Wt,
                                             const float* __restrict__ bias,
                                             unsigned short* __restrict__ Cg,
                                             unsigned short* __restrict__ Cs,
                                             int M, int K, int Fo,
                                             unsigned short* sA, unsigned short* sB) {
    const int t = threadIdx.x;
    const int lane = t & 63;
    const int wave = t >> 6;            // owns cols [colbase + wave*32, +32)
    const int l15 = lane & 15, quad = lane >> 4;
    const int row0 = bx * 64;
    const int colbase = by * 128;

    fx4 acc[4][2];
#pragma unroll
    for (int r = 0; r < 4; ++r)
#pragma unroll
        for (int c = 0; c < 2; ++c) acc[r][c] = (fx4){0.f, 0.f, 0.f, 0.f};

    auto stage = [&](int kc, int half) {
        unsigned short* dA = sA + half * 2048;
        unsigned short* dB = sB + half * 4096;
#pragma unroll
        for (int j = 0; j < 3; ++j) {
            int o = wave * 3 + j;           // [0, 12)
            int ak = kc + quad * 8;
            if (o < 4) {
                int ar = row0 + o * 16 + l15;
                if (ar >= M) ar = M - 1;
                gload_lds16(Ab + (size_t)ar * K + ak, dA + o * 512);
            } else {
                int bo = o - 4;             // [0, 8)
                int br = colbase + bo * 16 + l15;
                gload_lds16(Wt + (size_t)br * K + ak, dB + bo * 512);
            }
        }
    };

    stage(0, 0);
    __syncthreads();
    const int nt = K >> 5;
    int cur = 0;
    for (int tt = 0; tt < nt; ++tt) {
        if (tt + 1 < nt) stage((tt + 1) * 32, cur ^ 1);   // prefetch next K-step
        const unsigned short* cA = sA + cur * 2048;
        const unsigned short* cB = sB + cur * 4096;
        short8 a[4], b[2];
#pragma unroll
        for (int r = 0; r < 4; ++r)
            a[r] = *reinterpret_cast<const short8*>(&cA[r * 512 + lane * 8]);
#pragma unroll
        for (int c = 0; c < 2; ++c)
            b[c] = *reinterpret_cast<const short8*>(&cB[(wave * 2 + c) * 512 + lane * 8]);
#pragma unroll
        for (int r = 0; r < 4; ++r)
#pragma unroll
            for (int c = 0; c < 2; ++c)
                acc[r][c] = __builtin_amdgcn_mfma_f32_16x16x32_bf16(a[r], b[c], acc[r][c], 0, 0, 0);
        __syncthreads();
        cur ^= 1;
    }

#pragma unroll
    for (int r = 0; r < 4; ++r) {
#pragma unroll
        for (int reg = 0; reg < 4; ++reg) {
            int row = row0 + r * 16 + quad * 4 + reg;
            if (row >= M) continue;
#pragma unroll
            for (int c = 0; c < 2; ++c) {
                int f = colbase + wave * 32 + c * 16 + l15;
                if (f >= 2 * Fo) continue;
                bool isG = (f < Fo);
                int col = isG ? f : f - Fo;
                float badd = isG ? 0.f : bias[col];
                unsigned short* basep = isG ? Cg : Cs;
                basep[(size_t)row * Fo + col] = f2b(acc[r][c][reg] + badd);
            }
        }
    }
}

__global__ __launch_bounds__(256) void gemm_mfma(const unsigned short* __restrict__ Ab,
                                                 const unsigned short* __restrict__ Wt,
                                                 const float* __restrict__ bias,
                                                 unsigned short* __restrict__ Cg,
                                                 unsigned short* __restrict__ Cs,
                                                 int M, int K, int Fo) {
    __shared__ unsigned short sA[2 * 64 * 32];
    __shared__ unsigned short sB[2 * 128 * 32];
    gemm2ph_body(blockIdx.x, blockIdx.y, Ab, Wt, bias, Cg, Cs, M, K, Fo, sA, sB);
}

// ---------------- pull aggregation + fused BN/ReLU, Fo=128 ----------------
// Software-pipelined unroll-16: 16 gathers + 16 scalar rec-loads in flight/wave.

template <bool RELU>
__global__ __launch_bounds__(256) void agg128_kernel(
    const int* __restrict__ rowstart, const unsigned* __restrict__ eprec4,
    const unsigned* __restrict__ hw, const unsigned* __restrict__ selfC,
    const float* __restrict__ g, const float* __restrict__ be,
    const float* __restrict__ mu, const float* __restrict__ va,
    unsigned* __restrict__ out) {
    int wave = threadIdx.x >> 6;
    int lane = threadIdx.x & 63;
    int n = blockIdx.x * 4 + wave;
    if (n >= NN) return;
    unsigned scp = selfC[n * 64 + lane];
    float acc0 = blo(scp), acc1 = bhi(scp);
    int beg = rowstart[n], end = rowstart[n + 1];
    int i = beg;

    if (i + 16 <= end) {
        unsigned e[16];
        {
            int ifl = __builtin_amdgcn_readfirstlane(i);
#pragma unroll
            for (int k = 0; k < 16; ++k) e[k] = eprec4[ifl + k];
        }
        for (; i + 32 <= end; i += 16) {
            unsigned v[16];
#pragma unroll
            for (int k = 0; k < 16; ++k) v[k] = hw[(e[k] >> 16) * 64u + lane];
            unsigned en[16];
            {
                int ifl = __builtin_amdgcn_readfirstlane(i + 16);
#pragma unroll
                for (int k = 0; k < 16; ++k) en[k] = eprec4[ifl + k];
            }
#pragma unroll
            for (int k = 0; k < 16; ++k) {
                float w = blo(e[k]);
                acc0 += blo(v[k]) * w;
                acc1 += bhi(v[k]) * w;
            }
#pragma unroll
            for (int k = 0; k < 16; ++k) e[k] = en[k];
        }
        unsigned v[16];
#pragma unroll
        for (int k = 0; k < 16; ++k) v[k] = hw[(e[k] >> 16) * 64u + lane];
#pragma unroll
        for (int k = 0; k < 16; ++k) {
            float w = blo(e[k]);
            acc0 += blo(v[k]) * w;
            acc1 += bhi(v[k]) * w;
        }
        i += 16;
    }
    for (; i + 4 <= end; i += 4) {
        unsigned e0 = eprec4[i], e1 = eprec4[i + 1], e2 = eprec4[i + 2], e3 = eprec4[i + 3];
        unsigned v0 = hw[(e0 >> 16) * 64u + lane];
        unsigned v1 = hw[(e1 >> 16) * 64u + lane];
        unsigned v2 = hw[(e2 >> 16) * 64u + lane];
        unsigned v3 = hw[(e3 >> 16) * 64u + lane];
        float w0 = blo(e0), w1 = blo(e1), w2 = blo(e2), w3 = blo(e3);
        acc0 += blo(v0) * w0; acc1 += bhi(v0) * w0;
        acc0 += blo(v1) * w1; acc1 += bhi(v1) * w1;
        acc0 += blo(v2) * w2; acc1 += bhi(v2) * w2;
        acc0 += blo(v3) * w3; acc1 += bhi(v3) * w3;
    }
    for (; i < end; ++i) {
        unsigned e = eprec4[i];
        unsigned v = hw[(e >> 16) * 64u + lane];
        float w = blo(e);
        acc0 += blo(v) * w; acc1 += bhi(v) * w;
    }
    float2 m2 = reinterpret_cast<const float2*>(mu)[lane];
    float2 v2f = reinterpret_cast<const float2*>(va)[lane];
    float2 g2 = reinterpret_cast<const float2*>(g)[lane];
    float2 b2 = reinterpret_cast<const float2*>(be)[lane];
    float r0 = (acc0 - m2.x) * rsqrtf(v2f.x + EPSV) * g2.x + b2.x;
    float r1 = (acc1 - m2.y) * rsqrtf(v2f.y + EPSV) * g2.y + b2.y;
    if (RELU) {
        r0 = fmaxf(r0, 0.f);
        r1 = fmaxf(r1, 0.f);
    }
    out[n * 64 + lane] = pack2(r0, r1);
}

// ---------------- final layer aggregation, Fo=40, fp32 out ----------------

__global__ __launch_bounds__(256) void agg40_kernel(
    const int* __restrict__ rowstart, const unsigned* __restrict__ eprec4,
    const unsigned* __restrict__ hw, const unsigned* __restrict__ selfC,
    const float* __restrict__ g, const float* __restrict__ be,
    const float* __restrict__ mu, const float* __restrict__ va,
    float* __restrict__ out) {
    int wave = threadIdx.x >> 6;
    int lane = threadIdx.x & 63;
    int n = blockIdx.x * 4 + wave;
    if (n >= NN) return;
    int grp = lane / 20;
    int fl = lane - grp * 20;
    float acc0 = 0.f, acc1 = 0.f;
    int beg = rowstart[n], end = rowstart[n + 1];
    if (grp < 3) {
        int i = beg + grp;
        for (; i + 9 < end; i += 12) {
            unsigned e0 = eprec4[i], e1 = eprec4[i + 3], e2 = eprec4[i + 6], e3 = eprec4[i + 9];
            unsigned v0 = hw[(e0 >> 16) * 20u + fl];
            unsigned v1 = hw[(e1 >> 16) * 20u + fl];
            unsigned v2 = hw[(e2 >> 16) * 20u + fl];
            unsigned v3 = hw[(e3 >> 16) * 20u + fl];
            float w0 = blo(e0), w1 = blo(e1), w2 = blo(e2), w3 = blo(e3);
            acc0 += blo(v0) * w0; acc1 += bhi(v0) * w0;
            acc0 += blo(v1) * w1; acc1 += bhi(v1) * w1;
            acc0 += blo(v2) * w2; acc1 += bhi(v2) * w2;
            acc0 += blo(v3) * w3; acc1 += bhi(v3) * w3;
        }
        for (; i < end; i += 3) {
            unsigned e = eprec4[i];
            unsigned v = hw[(e >> 16) * 20u + fl];
            float w = blo(e);
            acc0 += blo(v) * w;
            acc1 += bhi(v) * w;
        }
    }
    acc0 += __shfl(acc0, lane + 20) + __shfl(acc0, lane + 40);
    acc1 += __shfl(acc1, lane + 20) + __shfl(acc1, lane + 40);
    if (lane < 20) {
        int f0 = lane * 2;
        unsigned scp = selfC[n * 20 + lane];
        acc0 += blo(scp);
        acc1 += bhi(scp);
        float2 m2 = reinterpret_cast<const float2*>(mu)[lane];
        float2 v2f = reinterpret_cast<const float2*>(va)[lane];
        float2 g2 = reinterpret_cast<const float2*>(g)[lane];
        float2 b2 = reinterpret_cast<const float2*>(be)[lane];
        float r0 = (acc0 - m2.x) * rsqrtf(v2f.x + EPSV) * g2.x + b2.x;
        float r1 = (acc1 - m2.y) * rsqrtf(v2f.y + EPSV) * g2.y + b2.y;
        *reinterpret_cast<float2*>(&out[(size_t)n * 40 + f0]) = make_float2(r0, r1);
    }
}

// ---------------- launch ----------------

extern "C" void kernel_launch(void* const* d_in, const int* in_sizes, int n_in,
                              void* d_out, int out_size, void* d_ws, size_t ws_size,
                              hipStream_t stream) {
    const float* x = (const float*)d_in[0];
    const int* ei = (const int*)d_in[1];
    const float* ew = (const float*)d_in[2];

    const float* wg[3]  = {(const float*)d_in[3],  (const float*)d_in[10], (const float*)d_in[17]};
    const float* wsf[3] = {(const float*)d_in[4],  (const float*)d_in[11], (const float*)d_in[18]};
    const float* bs[3]  = {(const float*)d_in[5],  (const float*)d_in[12], (const float*)d_in[19]};
    const float* gm[3]  = {(const float*)d_in[6],  (const float*)d_in[13], (const float*)d_in[20]};
    const float* bt[3]  = {(const float*)d_in[7],  (const float*)d_in[14], (const float*)d_in[21]};
    const float* mu[3]  = {(const float*)d_in[8],  (const float*)d_in[15], (const float*)d_in[22]};
    const float* vr[3]  = {(const float*)d_in[9],  (const float*)d_in[16], (const float*)d_in[23]};

    // workspace layout (float-sized slots), 14007584 floats = 56.0 MB total.
    // Aliased regions (launch order: hist, colsum, totsum, scanB, scanC, base,
    // fill2, dinv, rescale, gemm1, agg1, gemm2, agg2, gemm3, agg40):
    //   R1 [cnt 1.6M | prefix 1.6M] -> bufHW 3.2M   (cnt/prefix dead after fill2;
    //                                                gemm1 writes bufHW after rescale)
    //   R3 [wtmp 1M | spare]        -> bufSb 3.2M   (wtmp dead after rescale)
    //   R2 [xb 6.4M]                -> bufH 3.2M    (xb dead after gemm1; agg1 writes bufH)
    float* W = (float*)d_ws;
    float* dinv      = W + 0;                     // [0, 50048)
    int*   rowstart  = (int*)(W + 50048);         // [50048, 100064)
    unsigned* tot    = (unsigned*)(W + 100064);   // [100064, 150112)
    int*   bsum      = (int*)(W + 150112);        // [150112, 150176)
    int*   bpre      = (int*)(W + 150176);        // [150176, 150240)
    unsigned* eprec4 = (unsigned*)(W + 150240);   // [150240, 1150240)
    unsigned short* Wt1 = (unsigned short*)(W + 1150240);   // [1150240, 1183008)
    unsigned short* Wt2 = (unsigned short*)(W + 1183008);   // [1183008, 1199392)
    unsigned short* Wt3 = (unsigned short*)(W + 1199392);   // [1199392, 1207584)
    unsigned short* cnt = (unsigned short*)(W + 1207584);       // [1207584, 2807584) u16[64][50000]
    unsigned short* prefix = (unsigned short*)(W + 2807584);    // [2807584, 4407584) u16[64][50000]
    unsigned short* bufHW = (unsigned short*)(W + 1207584);     // aliases cnt+prefix (3.2M floats)
    float* wtmp      = W + 4407584;               // [4407584, 5407584)
    unsigned short* bufSb = (unsigned short*)(W + 4407584);     // aliases wtmp+spare [4407584, 7607584)
    unsigned short* xb  = (unsigned short*)(W + 7607584);       // [7607584, 14007584) — 6.4M floats
    unsigned short* bufH = (unsigned short*)(W + 7607584);      // aliases xb front (3.2M)

    const int B = 256;
    const int SB = 49;
    const int GX = 782;     // (NN+63)/64

    // weight conversions (tiny)
    setup_kernel<<<WB1 + WB2 + WB3, B, 0, stream>>>(
        wg[0], wsf[0], Wt1, wg[1], wsf[1], Wt2, wg[2], wsf[2], Wt3);

    // H1: LDS histograms (64 chunks) + x->bf16 conversion co-scheduled
    hist_kernel<<<NB + XB, B, 0, stream>>>(ei, (const float4*)x, (uint2*)xb, cnt);

    // CSR build: totals -> rowstart -> prefix -> scatter -> dinv -> rescale
    colsum_kernel<<<391, B, 0, stream>>>(cnt, tot);
    totsum_kernel<<<SB, 1024, 0, stream>>>(tot, bsum);
    scanB_kernel<<<1, 64, 0, stream>>>(bsum, bpre, SB);
    scanC_kernel<<<SB, 1024, 0, stream>>>(tot, bpre, rowstart);
    base_kernel<<<391, B, 0, stream>>>(cnt, prefix);
    fill2_kernel<<<NB * 4, B, 0, stream>>>(ei, ew, rowstart, prefix, eprec4, wtmp);
    dinv_kernel<<<(NN + 3) / 4, B, 0, stream>>>(rowstart, wtmp, dinv);
    rescale_kernel<<<(NN + 3) / 4, B, 0, stream>>>(rowstart, wtmp, dinv, eprec4);

    const int aggGrid = (NN + 3) / 4;
    dim3 g2(GX, 2), g1(GX, 1);

    // layer 1: xb bf16 [N,256] -> 128   (cnt/prefix/wtmp dead; bufHW/bufSb safe)
    gemm_mfma<<<g2, B, 0, stream>>>(xb, Wt1, bs[0], bufHW, bufSb, NN, 256, 128);
    // agg1 writes bufH over dead xb
    agg128_kernel<true><<<aggGrid, B, 0, stream>>>(rowstart, eprec4, (const unsigned*)bufHW,
                                                   (const unsigned*)bufSb, gm[0], bt[0], mu[0], vr[0],
                                                   (unsigned*)bufH);

    // layer 2: h bf16 [N,128] -> 128
    gemm_mfma<<<g2, B, 0, stream>>>(bufH, Wt2, bs[1], bufHW, bufSb, NN, 128, 128);
    agg128_kernel<true><<<aggGrid, B, 0, stream>>>(rowstart, eprec4, (const unsigned*)bufHW,
                                                   (const unsigned*)bufSb, gm[1], bt[1], mu[1], vr[1],
                                                   (unsigned*)bufH);

    // layer 3: h bf16 [N,128] -> 40 (cols padded to 128), fp32 out
    gemm_mfma<<<g1, B, 0, stream>>>(bufH, Wt3, bs[2], bufHW, bufSb, NN, 128, 40);
    agg40_kernel<<<aggGrid, B, 0, stream>>>(rowstart, eprec4, (const unsigned*)bufHW,
                                            (const unsigned*)bufSb, gm[2], bt[2], mu[2], vr[2],
                                            (float*)d_out);
}

// Round 10
// 379.614 us; speedup vs baseline: 1.1956x; 1.1956x over previous
//
#include <hip/hip_runtime.h>
#include <hip/hip_bf16.h>

#define NN 50000
#define EE 1000000
static constexpr float EPSV = 1e-3f;
static constexpr float FIXSCALE = 16777216.f;  // 2^24

typedef __attribute__((ext_vector_type(8))) short short8;
typedef __attribute__((ext_vector_type(4))) float fx4;

__device__ inline float blo(unsigned u) { return __uint_as_float(u << 16); }
__device__ inline float bhi(unsigned u) { return __uint_as_float(u & 0xffff0000u); }
__device__ inline unsigned short f2b(float f) {
    __hip_bfloat16 h = __float2bfloat16(f);
    return *(unsigned short*)&h;
}
__device__ inline unsigned pack2(float a, float b) {
    return (unsigned)f2b(a) | ((unsigned)f2b(b) << 16);
}

// async global->LDS DMA, 16 B per lane
__device__ inline void gload_lds16(const unsigned short* g, unsigned short* ldsbase) {
    __builtin_amdgcn_global_load_lds(
        (const __attribute__((address_space(1))) unsigned int*)(const void*)g,
        (__attribute__((address_space(3))) unsigned int*)(void*)ldsbase, 16, 0, 0);
}

// ---------------- setupx: zero padded cnt64 + weight converts + x->bf16 ----------------

#define ZB 196     // ceil(50000/256) zero blocks (stride-8 u64 slots)
#define WB1 256
#define WB2 128
#define WB3 64
#define XB 12500   // NN*64 uint2 / 256

__global__ void setupx_kernel(unsigned long long* __restrict__ cnt64p,
                              const float* __restrict__ wg1, const float* __restrict__ ws1,
                              unsigned short* __restrict__ Wt1,
                              const float* __restrict__ wg2, const float* __restrict__ ws2,
                              unsigned short* __restrict__ Wt2,
                              const float* __restrict__ wg3, const float* __restrict__ ws3,
                              unsigned short* __restrict__ Wt3,
                              const float4* __restrict__ x, uint2* __restrict__ xb) {
    int b = blockIdx.x;
    int t = threadIdx.x;
    if (b < ZB) {
        int i = b * 256 + t;
        if (i < NN) cnt64p[(size_t)i << 3] = 0ull;
    } else if (b < ZB + WB1) {
        int idx = (b - ZB) * 256 + t;       // [0, 65536)
        int n = idx >> 8, k = idx & 255;    // K=256, Fo=128, N2=256
        float v = (n < 128) ? wg1[(size_t)k * 128 + n]
                            : ws1[(size_t)k * 128 + (n - 128)];
        Wt1[idx] = f2b(v);
    } else if (b < ZB + WB1 + WB2) {
        int idx = (b - ZB - WB1) * 256 + t; // [0, 32768)
        int n = idx >> 7, k = idx & 127;
        float v = (n < 128) ? wg2[(size_t)k * 128 + n]
                            : ws2[(size_t)k * 128 + (n - 128)];
        Wt2[idx] = f2b(v);
    } else if (b < ZB + WB1 + WB2 + WB3) {
        int idx = (b - ZB - WB1 - WB2) * 256 + t; // [0, 16384)
        int n = idx >> 7, k = idx & 127;          // K=128, Fo=40, N2=128
        float v = 0.f;
        if (n < 40) v = wg3[(size_t)k * 40 + n];
        else if (n < 80) v = ws3[(size_t)k * 40 + (n - 40)];
        Wt3[idx] = f2b(v);
    } else {
        int i = (b - ZB - WB1 - WB2 - WB3) * 256 + t;  // [0, 3.2M)
        float4 v = x[i];
        xb[i] = make_uint2(pack2(v.x, v.y), pack2(v.z, v.w));
    }
}

// ---------------- MFMA dual GEMM body: 64x128 tile, BK=32, 2-phase dbuf ----------------

__device__ __forceinline__ void gemm2ph_body(int bx, int by,
                                             const unsigned short* __restrict__ Ab,
                                             const unsigned short* __restrict__ Wt,
                                             const float* __restrict__ bias,
                                             unsigned short* __restrict__ Cg,
                                             unsigned short* __restrict__ Cs,
                                             int M, int K, int Fo,
                                             unsigned short* sA, unsigned short* sB) {
    const int t = threadIdx.x;
    const int lane = t & 63;
    const int wave = t >> 6;            // owns cols [colbase + wave*32, +32)
    const int l15 = lane & 15, quad = lane >> 4;
    const int row0 = bx * 64;
    const int colbase = by * 128;

    fx4 acc[4][2];
#pragma unroll
    for (int r = 0; r < 4; ++r)
#pragma unroll
        for (int c = 0; c < 2; ++c) acc[r][c] = (fx4){0.f, 0.f, 0.f, 0.f};

    auto stage = [&](int kc, int half) {
        unsigned short* dA = sA + half * 2048;
        unsigned short* dB = sB + half * 4096;
#pragma unroll
        for (int j = 0; j < 3; ++j) {
            int o = wave * 3 + j;           // [0, 12)
            int ak = kc + quad * 8;
            if (o < 4) {
                int ar = row0 + o * 16 + l15;
                if (ar >= M) ar = M - 1;
                gload_lds16(Ab + (size_t)ar * K + ak, dA + o * 512);
            } else {
                int bo = o - 4;             // [0, 8)
                int br = colbase + bo * 16 + l15;
                gload_lds16(Wt + (size_t)br * K + ak, dB + bo * 512);
            }
        }
    };

    stage(0, 0);
    __syncthreads();
    const int nt = K >> 5;
    int cur = 0;
    for (int tt = 0; tt < nt; ++tt) {
        if (tt + 1 < nt) stage((tt + 1) * 32, cur ^ 1);   // prefetch next K-step
        const unsigned short* cA = sA + cur * 2048;
        const unsigned short* cB = sB + cur * 4096;
        short8 a[4], b[2];
#pragma unroll
        for (int r = 0; r < 4; ++r)
            a[r] = *reinterpret_cast<const short8*>(&cA[r * 512 + lane * 8]);
#pragma unroll
        for (int c = 0; c < 2; ++c)
            b[c] = *reinterpret_cast<const short8*>(&cB[(wave * 2 + c) * 512 + lane * 8]);
#pragma unroll
        for (int r = 0; r < 4; ++r)
#pragma unroll
            for (int c = 0; c < 2; ++c)
                acc[r][c] = __builtin_amdgcn_mfma_f32_16x16x32_bf16(a[r], b[c], acc[r][c], 0, 0, 0);
        __syncthreads();
        cur ^= 1;
    }

#pragma unroll
    for (int r = 0; r < 4; ++r) {
#pragma unroll
        for (int reg = 0; reg < 4; ++reg) {
            int row = row0 + r * 16 + quad * 4 + reg;
            if (row >= M) continue;
#pragma unroll
            for (int c = 0; c < 2; ++c) {
                int f = colbase + wave * 32 + c * 16 + l15;
                if (f >= 2 * Fo) continue;
                bool isG = (f < Fo);
                int col = isG ? f : f - Fo;
                float badd = isG ? 0.f : bias[col];
                unsigned short* basep = isG ? Cg : Cs;
                basep[(size_t)row * Fo + col] = f2b(acc[r][c][reg] + badd);
            }
        }
    }
}

// ---------------- mega: residency-fixed atomic pass + layer-1 GEMM ----------------
// R2/R9 insight: atomic blocks retire TOGETHER at t=58us (TCC round-robin), so
// they must not hold all CU slots. AB=256 grid-stride ILP-16 blocks (1/CU) keep
// the TCC saturated while 5 slots/CU run gemm1 blocks concurrently from t=0.

#define AB 256
#define GX 782     // (NN+63)/64
#define GB 1564    // GX * 2

__global__ __launch_bounds__(256) void mega_kernel(
    const int* __restrict__ ei, const float* __restrict__ ew,
    unsigned long long* __restrict__ cnt64p, unsigned* __restrict__ rank,
    const unsigned short* __restrict__ xb, const unsigned short* __restrict__ Wt1,
    const float* __restrict__ bias1,
    unsigned short* __restrict__ Cg, unsigned short* __restrict__ Cs) {
    __shared__ unsigned short sA[2 * 64 * 32];
    __shared__ unsigned short sB[2 * 128 * 32];
    int b = blockIdx.x;
    if (b < AB) {
        int gtid = b * 256 + threadIdx.x;   // [0, 65536)
#pragma unroll
        for (int g = 0; g < 2; ++g) {
            int d[8];
            unsigned fx[8];
            bool val[8];
#pragma unroll
            for (int j = 0; j < 8; ++j) {
                int e = (g * 8 + j) * 65536 + gtid;
                val[j] = (e < EE);
                if (val[j]) {
                    d[j] = ei[EE + e];
                    fx[j] = __float2uint_rn(ew[e] * FIXSCALE);
                }
            }
#pragma unroll
            for (int j = 0; j < 8; ++j) {
                if (val[j]) {
                    int e = (g * 8 + j) * 65536 + gtid;
                    unsigned long long old =
                        atomicAdd(&cnt64p[(size_t)d[j] << 3],
                                  0x100000000ull | (unsigned long long)fx[j]);
                    rank[e] = (unsigned)(old >> 32);
                }
            }
        }
        return;
    }
    int gi = b - AB;
    int by = gi / GX;
    int bx = gi - by * GX;
    gemm2ph_body(bx, by, xb, Wt1, bias1, Cg, Cs, NN, 256, 128, sA, sB);
}

// ---------------- CSR build (padded cnt64 reads) ----------------

__global__ __launch_bounds__(1024) void dinvsum_kernel(const unsigned long long* __restrict__ cnt64p,
                                                       float* __restrict__ dinv,
                                                       int* __restrict__ bsum) {
    __shared__ int s[1024];
    const int t = threadIdx.x;
    int idx = blockIdx.x * 1024 + t;
    unsigned long long cv = 0ull;
    if (idx < NN) cv = cnt64p[(size_t)idx << 3];
    float deg = (float)(unsigned)cv * (1.f / FIXSCALE);
    if (idx < NN) dinv[idx] = (deg > 0.f) ? rsqrtf(deg) : 0.f;
    s[t] = (int)(unsigned)(cv >> 32);
    __syncthreads();
#pragma unroll
    for (int off = 512; off > 0; off >>= 1) {
        if (t < off) s[t] += s[t + off];
        __syncthreads();
    }
    if (t == 0) bsum[blockIdx.x] = s[0];
}

__global__ __launch_bounds__(64) void scanB_kernel(const int* __restrict__ bsum,
                                                   int* __restrict__ bpre, int nb) {
    int t = threadIdx.x;
    int v = (t < nb) ? bsum[t] : 0;
    int own = v;
#pragma unroll
    for (int off = 1; off < 64; off <<= 1) {
        int u = __shfl_up(v, off);
        if (t >= off) v += u;
    }
    if (t < nb) bpre[t] = v - own;
}

__global__ __launch_bounds__(1024) void scanC_kernel(const unsigned long long* __restrict__ cnt64p,
                                                     const int* __restrict__ bpre,
                                                     int* __restrict__ rowstart) {
    __shared__ int s[1024];
    const int t = threadIdx.x;
    int idx = blockIdx.x * 1024 + t;
    int v = (idx < NN) ? (int)(unsigned)(cnt64p[(size_t)idx << 3] >> 32) : 0;
    s[t] = v;
    __syncthreads();
#pragma unroll
    for (int off = 1; off < 1024; off <<= 1) {
        int u = (t >= off) ? s[t - off] : 0;
        __syncthreads();
        s[t] += u;
        __syncthreads();
    }
    if (idx < NN) rowstart[idx] = s[t] - v + bpre[blockIdx.x];
    if (idx == 0) rowstart[NN] = EE;
}

// atomic-free scatter: 4-byte records (src:16 | w:bf16)
__global__ void fill_kernel(const int* __restrict__ ei, const float* __restrict__ ew,
                            const float* __restrict__ dinv, const int* __restrict__ rowstart,
                            const unsigned* __restrict__ rank, unsigned* __restrict__ eprec4) {
    int e = blockIdx.x * blockDim.x + threadIdx.x;
    if (e >= EE) return;
    int s = ei[e], d = ei[EE + e];
    int idx = rowstart[d] + (int)rank[e];
    float w = dinv[s] * ew[e] * dinv[d];
    eprec4[idx] = ((unsigned)s << 16) | (unsigned)f2b(w);
}

// standalone GEMM (layers 2/3)
__global__ __launch_bounds__(256) void gemm_mfma(const unsigned short* __restrict__ Ab,
                                                 const unsigned short* __restrict__ Wt,
                                                 const float* __restrict__ bias,
                                                 unsigned short* __restrict__ Cg,
                                                 unsigned short* __restrict__ Cs,
                                                 int M, int K, int Fo) {
    __shared__ unsigned short sA[2 * 64 * 32];
    __shared__ unsigned short sB[2 * 128 * 32];
    gemm2ph_body(blockIdx.x, blockIdx.y, Ab, Wt, bias, Cg, Cs, M, K, Fo, sA, sB);
}

// ---------------- pull aggregation + fused BN/ReLU, Fo=128 ----------------
// Software-pipelined unroll-16: 16 gathers + 16 scalar rec-loads in flight/wave.

template <bool RELU>
__global__ __launch_bounds__(256) void agg128_kernel(
    const int* __restrict__ rowstart, const unsigned* __restrict__ eprec4,
    const unsigned* __restrict__ hw, const unsigned* __restrict__ selfC,
    const float* __restrict__ g, const float* __restrict__ be,
    const float* __restrict__ mu, const float* __restrict__ va,
    unsigned* __restrict__ out) {
    int wave = threadIdx.x >> 6;
    int lane = threadIdx.x & 63;
    int n = blockIdx.x * 4 + wave;
    if (n >= NN) return;
    unsigned scp = selfC[n * 64 + lane];
    float acc0 = blo(scp), acc1 = bhi(scp);
    int beg = rowstart[n], end = rowstart[n + 1];
    int i = beg;

    if (i + 16 <= end) {
        unsigned e[16];
        {
            int ifl = __builtin_amdgcn_readfirstlane(i);
#pragma unroll
            for (int k = 0; k < 16; ++k) e[k] = eprec4[ifl + k];
        }
        for (; i + 32 <= end; i += 16) {
            unsigned v[16];
#pragma unroll
            for (int k = 0; k < 16; ++k) v[k] = hw[(e[k] >> 16) * 64u + lane];
            unsigned en[16];
            {
                int ifl = __builtin_amdgcn_readfirstlane(i + 16);
#pragma unroll
                for (int k = 0; k < 16; ++k) en[k] = eprec4[ifl + k];
            }
#pragma unroll
            for (int k = 0; k < 16; ++k) {
                float w = blo(e[k]);
                acc0 += blo(v[k]) * w;
                acc1 += bhi(v[k]) * w;
            }
#pragma unroll
            for (int k = 0; k < 16; ++k) e[k] = en[k];
        }
        unsigned v[16];
#pragma unroll
        for (int k = 0; k < 16; ++k) v[k] = hw[(e[k] >> 16) * 64u + lane];
#pragma unroll
        for (int k = 0; k < 16; ++k) {
            float w = blo(e[k]);
            acc0 += blo(v[k]) * w;
            acc1 += bhi(v[k]) * w;
        }
        i += 16;
    }
    for (; i + 4 <= end; i += 4) {
        unsigned e0 = eprec4[i], e1 = eprec4[i + 1], e2 = eprec4[i + 2], e3 = eprec4[i + 3];
        unsigned v0 = hw[(e0 >> 16) * 64u + lane];
        unsigned v1 = hw[(e1 >> 16) * 64u + lane];
        unsigned v2 = hw[(e2 >> 16) * 64u + lane];
        unsigned v3 = hw[(e3 >> 16) * 64u + lane];
        float w0 = blo(e0), w1 = blo(e1), w2 = blo(e2), w3 = blo(e3);
        acc0 += blo(v0) * w0; acc1 += bhi(v0) * w0;
        acc0 += blo(v1) * w1; acc1 += bhi(v1) * w1;
        acc0 += blo(v2) * w2; acc1 += bhi(v2) * w2;
        acc0 += blo(v3) * w3; acc1 += bhi(v3) * w3;
    }
    for (; i < end; ++i) {
        unsigned e = eprec4[i];
        unsigned v = hw[(e >> 16) * 64u + lane];
        float w = blo(e);
        acc0 += blo(v) * w; acc1 += bhi(v) * w;
    }
    float2 m2 = reinterpret_cast<const float2*>(mu)[lane];
    float2 v2f = reinterpret_cast<const float2*>(va)[lane];
    float2 g2 = reinterpret_cast<const float2*>(g)[lane];
    float2 b2 = reinterpret_cast<const float2*>(be)[lane];
    float r0 = (acc0 - m2.x) * rsqrtf(v2f.x + EPSV) * g2.x + b2.x;
    float r1 = (acc1 - m2.y) * rsqrtf(v2f.y + EPSV) * g2.y + b2.y;
    if (RELU) {
        r0 = fmaxf(r0, 0.f);
        r1 = fmaxf(r1, 0.f);
    }
    out[n * 64 + lane] = pack2(r0, r1);
}

// ---------------- final layer aggregation, Fo=40, fp32 out ----------------

__global__ __launch_bounds__(256) void agg40_kernel(
    const int* __restrict__ rowstart, const unsigned* __restrict__ eprec4,
    const unsigned* __restrict__ hw, const unsigned* __restrict__ selfC,
    const float* __restrict__ g, const float* __restrict__ be,
    const float* __restrict__ mu, const float* __restrict__ va,
    float* __restrict__ out) {
    int wave = threadIdx.x >> 6;
    int lane = threadIdx.x & 63;
    int n = blockIdx.x * 4 + wave;
    if (n >= NN) return;
    int grp = lane / 20;
    int fl = lane - grp * 20;
    float acc0 = 0.f, acc1 = 0.f;
    int beg = rowstart[n], end = rowstart[n + 1];
    if (grp < 3) {
        int i = beg + grp;
        for (; i + 9 < end; i += 12) {
            unsigned e0 = eprec4[i], e1 = eprec4[i + 3], e2 = eprec4[i + 6], e3 = eprec4[i + 9];
            unsigned v0 = hw[(e0 >> 16) * 20u + fl];
            unsigned v1 = hw[(e1 >> 16) * 20u + fl];
            unsigned v2 = hw[(e2 >> 16) * 20u + fl];
            unsigned v3 = hw[(e3 >> 16) * 20u + fl];
            float w0 = blo(e0), w1 = blo(e1), w2 = blo(e2), w3 = blo(e3);
            acc0 += blo(v0) * w0; acc1 += bhi(v0) * w0;
            acc0 += blo(v1) * w1; acc1 += bhi(v1) * w1;
            acc0 += blo(v2) * w2; acc1 += bhi(v2) * w2;
            acc0 += blo(v3) * w3; acc1 += bhi(v3) * w3;
        }
        for (; i < end; i += 3) {
            unsigned e = eprec4[i];
            unsigned v = hw[(e >> 16) * 20u + fl];
            float w = blo(e);
            acc0 += blo(v) * w;
            acc1 += bhi(v) * w;
        }
    }
    acc0 += __shfl(acc0, lane + 20) + __shfl(acc0, lane + 40);
    acc1 += __shfl(acc1, lane + 20) + __shfl(acc1, lane + 40);
    if (lane < 20) {
        int f0 = lane * 2;
        unsigned scp = selfC[n * 20 + lane];
        acc0 += blo(scp);
        acc1 += bhi(scp);
        float2 m2 = reinterpret_cast<const float2*>(mu)[lane];
        float2 v2f = reinterpret_cast<const float2*>(va)[lane];
        float2 g2 = reinterpret_cast<const float2*>(g)[lane];
        float2 b2 = reinterpret_cast<const float2*>(be)[lane];
        float r0 = (acc0 - m2.x) * rsqrtf(v2f.x + EPSV) * g2.x + b2.x;
        float r1 = (acc1 - m2.y) * rsqrtf(v2f.y + EPSV) * g2.y + b2.y;
        *reinterpret_cast<float2*>(&out[(size_t)n * 40 + f0]) = make_float2(r0, r1);
    }
}

// ---------------- launch ----------------

extern "C" void kernel_launch(void* const* d_in, const int* in_sizes, int n_in,
                              void* d_out, int out_size, void* d_ws, size_t ws_size,
                              hipStream_t stream) {
    const float* x = (const float*)d_in[0];
    const int* ei = (const int*)d_in[1];
    const float* ew = (const float*)d_in[2];

    const float* wg[3]  = {(const float*)d_in[3],  (const float*)d_in[10], (const float*)d_in[17]};
    const float* wsf[3] = {(const float*)d_in[4],  (const float*)d_in[11], (const float*)d_in[18]};
    const float* bs[3]  = {(const float*)d_in[5],  (const float*)d_in[12], (const float*)d_in[19]};
    const float* gm[3]  = {(const float*)d_in[6],  (const float*)d_in[13], (const float*)d_in[20]};
    const float* bt[3]  = {(const float*)d_in[7],  (const float*)d_in[14], (const float*)d_in[21]};
    const float* mu[3]  = {(const float*)d_in[8],  (const float*)d_in[15], (const float*)d_in[22]};
    const float* vr[3]  = {(const float*)d_in[9],  (const float*)d_in[16], (const float*)d_in[23]};

    // workspace layout (float-sized slots), 15857728 floats = 63.4 MB.
    // cnt64p now has its OWN region (gemm1 writes bufSb concurrently in mega).
    // Only alias: xb (dead after mega/gemm1) -> bufH (agg1 onwards).
    float* W = (float*)d_ws;
    float* dinv     = W + 100096;                 // [100096, 150144)
    unsigned* rank  = (unsigned*)(W + 150144);    // [150144, 1150144)
    int*   bsum     = (int*)(W + 1150144);        // [1150144, 1150208)
    int*   bpre     = (int*)(W + 1150208);        // [1150208, 1150272)
    int*   rowstart = (int*)(W + 1150272);        // [1150272, 1200384)
    unsigned* eprec4 = (unsigned*)(W + 1200384);  // [1200384, 2200384)
    unsigned short* Wt1 = (unsigned short*)(W + 2200384);     // [2200384, 2233152)
    unsigned short* Wt2 = (unsigned short*)(W + 2233152);     // [2233152, 2249536)
    unsigned short* Wt3 = (unsigned short*)(W + 2249536);     // [2249536, 2257728)
    unsigned short* xb  = (unsigned short*)(W + 2257728);     // [2257728, 8657728)
    unsigned short* bufH = (unsigned short*)(W + 2257728);    // aliases xb
    unsigned short* bufHW = (unsigned short*)(W + 8657728);   // [8657728, 11857728)
    unsigned short* bufSb = (unsigned short*)(W + 11857728);  // [11857728, 15057728)
    unsigned long long* cnt64p = (unsigned long long*)(W + 15057728);  // [15057728, 15857728)

    const int B = 256;
    const int SB = 49;

    // setupx: zero cnt64p slots + weight conversions + x->bf16
    setupx_kernel<<<ZB + WB1 + WB2 + WB3 + XB, B, 0, stream>>>(
        cnt64p, wg[0], wsf[0], Wt1, wg[1], wsf[1], Wt2, wg[2], wsf[2], Wt3,
        (const float4*)x, (uint2*)xb);

    // mega: 256 grid-stride atomic blocks (1/CU) + gemm1 co-resident from t=0
    mega_kernel<<<AB + GB, B, 0, stream>>>(ei, ew, cnt64p, rank, xb, Wt1, bs[0],
                                           bufHW, bufSb);

    dinvsum_kernel<<<SB, 1024, 0, stream>>>(cnt64p, dinv, bsum);
    scanB_kernel<<<1, 64, 0, stream>>>(bsum, bpre, SB);
    scanC_kernel<<<SB, 1024, 0, stream>>>(cnt64p, bpre, rowstart);
    fill_kernel<<<(EE + B - 1) / B, B, 0, stream>>>(ei, ew, dinv, rowstart, rank, eprec4);

    const int aggGrid = (NN + 3) / 4;
    dim3 g2(GX, 2), g1(GX, 1);

    // layer 1 aggregation (gemm1 done in mega; bufH over dead xb)
    agg128_kernel<true><<<aggGrid, B, 0, stream>>>(rowstart, eprec4, (const unsigned*)bufHW,
                                                   (const unsigned*)bufSb, gm[0], bt[0], mu[0], vr[0],
                                                   (unsigned*)bufH);

    // layer 2: h bf16 [N,128] -> 128
    gemm_mfma<<<g2, B, 0, stream>>>(bufH, Wt2, bs[1], bufHW, bufSb, NN, 128, 128);
    agg128_kernel<true><<<aggGrid, B, 0, stream>>>(rowstart, eprec4, (const unsigned*)bufHW,
                                                   (const unsigned*)bufSb, gm[1], bt[1], mu[1], vr[1],
                                                   (unsigned*)bufH);

    // layer 3: h bf16 [N,128] -> 40 (cols padded to 128), fp32 out
    gemm_mfma<<<g1, B, 0, stream>>>(bufH, Wt3, bs[2], bufHW, bufSb, NN, 128, 40);
    agg40_kernel<<<aggGrid, B, 0, stream>>>(rowstart, eprec4, (const unsigned*)bufHW,
                                            (const unsigned*)bufSb, gm[2], bt[2], mu[2], vr[2],
                                            (float*)d_out);
}